// Round 1
// baseline (562.785 us; speedup 1.0000x reference)
//
#include <hip/hip_runtime.h>
#include <math.h>

// Problem constants (match reference)
static constexpr int BN = 8;      // batch
static constexpr int TS = 2048;   // sequence length
static constexpr int CE = 1024;   // embed dim
static constexpr int HD = 64;     // head size

// ---------------------------------------------------------------------------
// Kernel 1: QKV projection.  q/k/v[r][h] = sum_c x[r][c] * W{q,k,v}[c][h]
// One block = 16 rows of x staged in LDS; thread (r, cg) computes 4 head dims
// (h0 = cg*4) for all 3 matrices. W loads are float4, coalesced across cg.
// ---------------------------------------------------------------------------
__global__ __launch_bounds__(256) void qkv_proj_kernel(
    const float* __restrict__ x,
    const float* __restrict__ Wq,
    const float* __restrict__ Wk,
    const float* __restrict__ Wv,
    float* __restrict__ qo,
    float* __restrict__ ko,
    float* __restrict__ vo)
{
    __shared__ float xs[16 * 1028];   // 16 rows, stride 1028 (pad 4 -> 2-way banks max)
    const int tid = threadIdx.x;
    const long row0 = (long)blockIdx.x * 16;
    const float* xg = x + row0 * CE;

    // Stage 16x1024 floats (4096 float4, 16 per thread), coalesced.
    #pragma unroll
    for (int it = 0; it < 16; ++it) {
        int f = tid + it * 256;        // float4 index 0..4095
        int e = f * 4;
        int r = e >> 10, col = e & 1023;
        *(float4*)(&xs[r * 1028 + col]) = *(const float4*)(xg + e);
    }
    __syncthreads();

    const int r  = tid >> 4;
    const int h0 = (tid & 15) * 4;

    float aq[4] = {0.f,0.f,0.f,0.f};
    float ak[4] = {0.f,0.f,0.f,0.f};
    float av[4] = {0.f,0.f,0.f,0.f};

    for (int c4 = 0; c4 < CE; c4 += 4) {
        float4 x4 = *(const float4*)(&xs[r * 1028 + c4]);
        float xv[4] = {x4.x, x4.y, x4.z, x4.w};
        #pragma unroll
        for (int w = 0; w < 4; ++w) {
            const int cc = c4 + w;
            float4 wq = *(const float4*)(Wq + cc * HD + h0);
            float4 wk = *(const float4*)(Wk + cc * HD + h0);
            float4 wv = *(const float4*)(Wv + cc * HD + h0);
            aq[0] += xv[w] * wq.x; aq[1] += xv[w] * wq.y;
            aq[2] += xv[w] * wq.z; aq[3] += xv[w] * wq.w;
            ak[0] += xv[w] * wk.x; ak[1] += xv[w] * wk.y;
            ak[2] += xv[w] * wk.z; ak[3] += xv[w] * wk.w;
            av[0] += xv[w] * wv.x; av[1] += xv[w] * wv.y;
            av[2] += xv[w] * wv.z; av[3] += xv[w] * wv.w;
        }
    }

    const long orow = row0 + r;
    float4 q4 = {aq[0], aq[1], aq[2], aq[3]};
    float4 k4 = {ak[0], ak[1], ak[2], ak[3]};
    float4 v4 = {av[0], av[1], av[2], av[3]};
    *(float4*)(qo + orow * HD + h0) = q4;
    *(float4*)(ko + orow * HD + h0) = k4;
    *(float4*)(vo + orow * HD + h0) = v4;
}

// ---------------------------------------------------------------------------
// Kernel 2: causal flash attention over precomputed q,k,v (f32).
// Block = (batch b, 64-row Q tile qt). 256 threads = 16 row-groups x 16
// col-groups; thread owns 4x4 register tiles with interleaved (stride-16)
// row/col ownership so all hot LDS reads are <=2-way bank conflicts.
// Online softmax state (m, l, O[4][4]) per thread; P is wave-private in LDS.
// ---------------------------------------------------------------------------
__global__ __launch_bounds__(256) void attn_kernel(
    const float* __restrict__ qg,
    const float* __restrict__ kg,
    const float* __restrict__ vg,
    float* __restrict__ out)
{
    __shared__ float Qs[64 * 68];
    __shared__ float Ks[64 * 68];
    __shared__ float Vt[64 * 68];   // transposed: Vt[d][kj]
    __shared__ float Ps[64 * 68];

    const int tid = threadIdx.x;
    const int bq  = blockIdx.x;
    const int b   = bq >> 5;
    const int qt  = bq & 31;
    const int rg  = tid >> 4;      // 0..15
    const int cg  = tid & 15;      // 0..15

    // Stage Q tile [64][64] -> Qs (stride 68)
    const float* qtile = qg + (long)(b * TS + qt * 64) * HD;
    #pragma unroll
    for (int it = 0; it < 4; ++it) {
        int f = tid + it * 256;
        int e = f * 4;
        int rr = e >> 6, col = e & 63;
        *(float4*)(&Qs[rr * 68 + col]) = *(const float4*)(qtile + e);
    }

    float m_[4], l_[4], O_[4][4];
    #pragma unroll
    for (int i = 0; i < 4; ++i) {
        m_[i] = -INFINITY; l_[i] = 0.f;
        #pragma unroll
        for (int u = 0; u < 4; ++u) O_[i][u] = 0.f;
    }

    for (int kt = 0; kt <= qt; ++kt) {
        __syncthreads();   // previous tile's K/V fully consumed
        const float* ktile = kg + (long)(b * TS + kt * 64) * HD;
        const float* vtile = vg + (long)(b * TS + kt * 64) * HD;
        #pragma unroll
        for (int it = 0; it < 4; ++it) {
            int f = tid + it * 256;
            int e = f * 4;
            int rr = e >> 6, col = e & 63;
            *(float4*)(&Ks[rr * 68 + col]) = *(const float4*)(ktile + e);
            float4 vv = *(const float4*)(vtile + e);
            Vt[(col + 0) * 68 + rr] = vv.x;
            Vt[(col + 1) * 68 + rr] = vv.y;
            Vt[(col + 2) * 68 + rr] = vv.z;
            Vt[(col + 3) * 68 + rr] = vv.w;
        }
        __syncthreads();

        // --- S = (Q K^T) for this thread's 4 rows x 4 cols ---
        float s[4][4];
        #pragma unroll
        for (int i = 0; i < 4; ++i)
            #pragma unroll
            for (int j = 0; j < 4; ++j) s[i][j] = 0.f;

        for (int d4 = 0; d4 < 64; d4 += 4) {
            float4 q4[4], k4[4];
            #pragma unroll
            for (int i = 0; i < 4; ++i)
                q4[i] = *(const float4*)(&Qs[(rg + 16 * i) * 68 + d4]);
            #pragma unroll
            for (int j = 0; j < 4; ++j)
                k4[j] = *(const float4*)(&Ks[(cg + 16 * j) * 68 + d4]);
            #pragma unroll
            for (int i = 0; i < 4; ++i)
                #pragma unroll
                for (int j = 0; j < 4; ++j)
                    s[i][j] += q4[i].x * k4[j].x + q4[i].y * k4[j].y +
                               q4[i].z * k4[j].z + q4[i].w * k4[j].w;
        }

        // --- scale, causal mask, online softmax update ---
        const bool diag = (kt == qt);
        #pragma unroll
        for (int i = 0; i < 4; ++i) {
            const int qi = rg + 16 * i;
            float tm = -INFINITY;
            #pragma unroll
            for (int j = 0; j < 4; ++j) {
                float sv = s[i][j] * 0.125f;
                if (diag && (cg + 16 * j) > qi) sv = -INFINITY;
                s[i][j] = sv;
                tm = fmaxf(tm, sv);
            }
            #pragma unroll
            for (int off = 1; off < 16; off <<= 1)
                tm = fmaxf(tm, __shfl_xor(tm, off, 16));

            const float mn = fmaxf(m_[i], tm);       // finite: col 0 never masked
            const float alpha = __expf(m_[i] - mn);  // 0 on first tile
            float rs = 0.f;
            #pragma unroll
            for (int j = 0; j < 4; ++j) {
                float p = __expf(s[i][j] - mn);
                Ps[qi * 68 + cg + 16 * j] = p;
                rs += p;
            }
            #pragma unroll
            for (int off = 1; off < 16; off <<= 1)
                rs += __shfl_xor(rs, off, 16);

            l_[i] = l_[i] * alpha + rs;
            m_[i] = mn;
            #pragma unroll
            for (int u = 0; u < 4; ++u) O_[i][u] *= alpha;
        }
        // (no barrier needed: each wave reads only P rows it wrote)

        // --- O += P * V ---
        for (int kj4 = 0; kj4 < 64; kj4 += 4) {
            float4 p4[4], v4[4];
            #pragma unroll
            for (int i = 0; i < 4; ++i)
                p4[i] = *(const float4*)(&Ps[(rg + 16 * i) * 68 + kj4]);
            #pragma unroll
            for (int u = 0; u < 4; ++u)
                v4[u] = *(const float4*)(&Vt[(cg + 16 * u) * 68 + kj4]);
            #pragma unroll
            for (int i = 0; i < 4; ++i)
                #pragma unroll
                for (int u = 0; u < 4; ++u)
                    O_[i][u] += p4[i].x * v4[u].x + p4[i].y * v4[u].y +
                                p4[i].z * v4[u].z + p4[i].w * v4[u].w;
        }
    }

    // --- epilogue: normalize and store ---
    #pragma unroll
    for (int i = 0; i < 4; ++i) {
        const float inv = 1.f / l_[i];
        const long row = (long)(b * TS + qt * 64 + rg + 16 * i);
        #pragma unroll
        for (int u = 0; u < 4; ++u)
            out[row * HD + cg + 16 * u] = O_[i][u] * inv;
    }
}

// ---------------------------------------------------------------------------
extern "C" void kernel_launch(void* const* d_in, const int* in_sizes, int n_in,
                              void* d_out, int out_size, void* d_ws, size_t ws_size,
                              hipStream_t stream) {
    const float* x  = (const float*)d_in[0];
    const float* Wq = (const float*)d_in[1];
    const float* Wk = (const float*)d_in[2];
    const float* Wv = (const float*)d_in[3];
    float* out = (float*)d_out;

    const size_t nqkv = (size_t)BN * TS * HD;   // 1,048,576 elems = 4 MB each
    float* qb = (float*)d_ws;
    float* kb = qb + nqkv;
    float* vb = kb + nqkv;

    // Projection: 16 rows per block -> 1024 blocks
    qkv_proj_kernel<<<(BN * TS) / 16, 256, 0, stream>>>(x, Wq, Wk, Wv, qb, kb, vb);
    // Attention: one block per (batch, 64-row q tile) -> 256 blocks
    attn_kernel<<<BN * (TS / 64), 256, 0, stream>>>(qb, kb, vb, out);
}

// Round 2
// 282.163 us; speedup vs baseline: 1.9945x; 1.9945x over previous
//
#include <hip/hip_runtime.h>
#include <math.h>

// Problem constants (match reference)
static constexpr int BN = 8;      // batch
static constexpr int TS = 2048;   // sequence length
static constexpr int CE = 1024;   // embed dim
static constexpr int HD = 64;     // head size

typedef __attribute__((ext_vector_type(8))) short bf16x8;
typedef __attribute__((ext_vector_type(4))) float f32x4;

__device__ __forceinline__ unsigned short f2bf(float f) {
    union { float f; unsigned u; } v; v.f = f;
    unsigned r = v.u + 0x7FFF + ((v.u >> 16) & 1);   // round-to-nearest-even
    return (unsigned short)(r >> 16);
}

// ---------------------------------------------------------------------------
// Kernel 0: W transpose + bf16 convert.  Wt[n][k] (n in 0..191 = q|k|v) from
// W_sel[k][n&63].  48 blocks: (matrix m, 64-wide k tile).
// ---------------------------------------------------------------------------
__global__ __launch_bounds__(256) void wt_kernel(
    const float* __restrict__ Wq, const float* __restrict__ Wk,
    const float* __restrict__ Wv, unsigned short* __restrict__ Wt)
{
    __shared__ float T[64 * 69];
    const int tid = threadIdx.x;
    const int m  = blockIdx.x >> 4;   // 0..2
    const int kt = blockIdx.x & 15;   // 0..15
    const float* W = (m == 0) ? Wq : (m == 1) ? Wk : Wv;
    const int k0 = kt * 64;

    #pragma unroll
    for (int it = 0; it < 4; ++it) {
        int idx = tid + it * 256;      // 0..1023
        int r = idx >> 4, nq = idx & 15;
        float4 v = *(const float4*)(W + (long)(k0 + r) * HD + nq * 4);
        T[r * 69 + nq * 4 + 0] = v.x;
        T[r * 69 + nq * 4 + 1] = v.y;
        T[r * 69 + nq * 4 + 2] = v.z;
        T[r * 69 + nq * 4 + 3] = v.w;
    }
    __syncthreads();
    #pragma unroll
    for (int it = 0; it < 2; ++it) {
        int idx = tid + it * 256;      // 0..511
        int n = idx >> 3, kq = idx & 7;
        unsigned short h[8];
        #pragma unroll
        for (int s = 0; s < 8; ++s)
            h[s] = f2bf(T[(kq * 8 + s) * 69 + n]);
        *(uint4*)(Wt + (long)(m * 64 + n) * CE + k0 + kq * 8) = *(uint4*)h;
    }
}

// ---------------------------------------------------------------------------
// Kernel 1: QKV projection as bf16 MFMA GEMM.
// C[16384][192] = x[16384][1024] * Wt^T ; BM=32, BK=64, double-buffered LDS.
// 4 waves: wave w owns rows 0..31 x cols [w*48, w*48+48) = 2x3 fragments of
// mfma_f32_16x16x32_bf16.  x converted f32->bf16 during reg-staged writes.
// ---------------------------------------------------------------------------
static constexpr int BM  = 32;
static constexpr int BK  = 64;
static constexpr int LDT = BK + 8;   // 72 (144 B stride -> <=2-way banks)
static constexpr int NTI = CE / BK;  // 16

__global__ __launch_bounds__(256) void qkv_mfma_kernel(
    const float* __restrict__ x, const unsigned short* __restrict__ Wt,
    float* __restrict__ qo, float* __restrict__ ko, float* __restrict__ vo)
{
    __shared__ __align__(16) unsigned short xL[2][BM * LDT];
    __shared__ __align__(16) unsigned short wL[2][192 * LDT];

    const int tid = threadIdx.x;
    const int l   = tid & 63, wv = tid >> 6;
    const int lr  = l & 15,  lhi = l >> 4;
    const long row0 = (long)blockIdx.x * BM;

    f32x4 acc[2][3];
    #pragma unroll
    for (int i = 0; i < 2; ++i)
        #pragma unroll
        for (int j = 0; j < 3; ++j)
            acc[i][j] = (f32x4){0.f, 0.f, 0.f, 0.f};

    float4 xr[2];
    uint4  wr[6];

    // ---- load + stage chunk 0
    #pragma unroll
    for (int it = 0; it < 2; ++it) {
        int idx = tid + it * 256; int r = idx >> 4, kq = idx & 15;
        xr[it] = *(const float4*)(x + (row0 + r) * CE + kq * 4);
    }
    #pragma unroll
    for (int it = 0; it < 6; ++it) {
        int idx = tid + it * 256; int n = idx >> 3, kq = idx & 7;
        wr[it] = *(const uint4*)(Wt + (long)n * CE + kq * 8);
    }
    #pragma unroll
    for (int it = 0; it < 2; ++it) {
        int idx = tid + it * 256; int r = idx >> 4, kq = idx & 15;
        unsigned short h[4] = { f2bf(xr[it].x), f2bf(xr[it].y),
                                f2bf(xr[it].z), f2bf(xr[it].w) };
        *(uint2*)(&xL[0][r * LDT + kq * 4]) = *(uint2*)h;
    }
    #pragma unroll
    for (int it = 0; it < 6; ++it) {
        int idx = tid + it * 256; int n = idx >> 3, kq = idx & 7;
        *(uint4*)(&wL[0][n * LDT + kq * 8]) = wr[it];
    }
    __syncthreads();

    for (int t = 0; t < NTI; ++t) {
        const int cur = t & 1;
        const int k0n = (t + 1) * BK;
        if (t < NTI - 1) {
            #pragma unroll
            for (int it = 0; it < 2; ++it) {
                int idx = tid + it * 256; int r = idx >> 4, kq = idx & 15;
                xr[it] = *(const float4*)(x + (row0 + r) * CE + k0n + kq * 4);
            }
            #pragma unroll
            for (int it = 0; it < 6; ++it) {
                int idx = tid + it * 256; int n = idx >> 3, kq = idx & 7;
                wr[it] = *(const uint4*)(Wt + (long)n * CE + k0n + kq * 8);
            }
        }
        // compute on buf[cur]
        #pragma unroll
        for (int kk = 0; kk < 2; ++kk) {
            bf16x8 a[2], b[3];
            #pragma unroll
            for (int i = 0; i < 2; ++i)
                a[i] = *(const bf16x8*)(&xL[cur][(16 * i + lr) * LDT + kk * 32 + lhi * 8]);
            #pragma unroll
            for (int j = 0; j < 3; ++j)
                b[j] = *(const bf16x8*)(&wL[cur][(wv * 48 + 16 * j + lr) * LDT + kk * 32 + lhi * 8]);
            #pragma unroll
            for (int i = 0; i < 2; ++i)
                #pragma unroll
                for (int j = 0; j < 3; ++j)
                    acc[i][j] = __builtin_amdgcn_mfma_f32_16x16x32_bf16(
                        a[i], b[j], acc[i][j], 0, 0, 0);
        }
        if (t < NTI - 1) {
            __syncthreads();          // all waves done reading buf[cur^1] (prev) & cur
            const int nb = cur ^ 1;
            #pragma unroll
            for (int it = 0; it < 2; ++it) {
                int idx = tid + it * 256; int r = idx >> 4, kq = idx & 15;
                unsigned short h[4] = { f2bf(xr[it].x), f2bf(xr[it].y),
                                        f2bf(xr[it].z), f2bf(xr[it].w) };
                *(uint2*)(&xL[nb][r * LDT + kq * 4]) = *(uint2*)h;
            }
            #pragma unroll
            for (int it = 0; it < 6; ++it) {
                int idx = tid + it * 256; int n = idx >> 3, kq = idx & 7;
                *(uint4*)(&wL[nb][n * LDT + kq * 8]) = wr[it];
            }
            __syncthreads();
        }
    }

    // ---- epilogue: C/D layout col=lane&15, row=4*(lane>>4)+reg  [m89]
    #pragma unroll
    for (int j = 0; j < 3; ++j) {
        const int n0 = wv * 48 + 16 * j;
        float* outp = (n0 < 64) ? qo : (n0 < 128) ? ko : vo;
        const int h0 = (n0 & 63) + lr;
        #pragma unroll
        for (int i = 0; i < 2; ++i)
            #pragma unroll
            for (int r = 0; r < 4; ++r) {
                long rowg = row0 + 16 * i + lhi * 4 + r;
                outp[rowg * HD + h0] = acc[i][j][r];
            }
    }
}

// ---------------------------------------------------------------------------
// Kernel 2: causal flash attention (f32, unchanged from R1).
// ---------------------------------------------------------------------------
__global__ __launch_bounds__(256) void attn_kernel(
    const float* __restrict__ qg,
    const float* __restrict__ kg,
    const float* __restrict__ vg,
    float* __restrict__ out)
{
    __shared__ float Qs[64 * 68];
    __shared__ float Ks[64 * 68];
    __shared__ float Vt[64 * 68];   // transposed: Vt[d][kj]
    __shared__ float Ps[64 * 68];

    const int tid = threadIdx.x;
    const int bq  = blockIdx.x;
    const int b   = bq >> 5;
    const int qt  = bq & 31;
    const int rg  = tid >> 4;      // 0..15
    const int cg  = tid & 15;      // 0..15

    const float* qtile = qg + (long)(b * TS + qt * 64) * HD;
    #pragma unroll
    for (int it = 0; it < 4; ++it) {
        int f = tid + it * 256;
        int e = f * 4;
        int rr = e >> 6, col = e & 63;
        *(float4*)(&Qs[rr * 68 + col]) = *(const float4*)(qtile + e);
    }

    float m_[4], l_[4], O_[4][4];
    #pragma unroll
    for (int i = 0; i < 4; ++i) {
        m_[i] = -INFINITY; l_[i] = 0.f;
        #pragma unroll
        for (int u = 0; u < 4; ++u) O_[i][u] = 0.f;
    }

    for (int kt = 0; kt <= qt; ++kt) {
        __syncthreads();
        const float* ktile = kg + (long)(b * TS + kt * 64) * HD;
        const float* vtile = vg + (long)(b * TS + kt * 64) * HD;
        #pragma unroll
        for (int it = 0; it < 4; ++it) {
            int f = tid + it * 256;
            int e = f * 4;
            int rr = e >> 6, col = e & 63;
            *(float4*)(&Ks[rr * 68 + col]) = *(const float4*)(ktile + e);
            float4 vv = *(const float4*)(vtile + e);
            Vt[(col + 0) * 68 + rr] = vv.x;
            Vt[(col + 1) * 68 + rr] = vv.y;
            Vt[(col + 2) * 68 + rr] = vv.z;
            Vt[(col + 3) * 68 + rr] = vv.w;
        }
        __syncthreads();

        float s[4][4];
        #pragma unroll
        for (int i = 0; i < 4; ++i)
            #pragma unroll
            for (int j = 0; j < 4; ++j) s[i][j] = 0.f;

        for (int d4 = 0; d4 < 64; d4 += 4) {
            float4 q4[4], k4[4];
            #pragma unroll
            for (int i = 0; i < 4; ++i)
                q4[i] = *(const float4*)(&Qs[(rg + 16 * i) * 68 + d4]);
            #pragma unroll
            for (int j = 0; j < 4; ++j)
                k4[j] = *(const float4*)(&Ks[(cg + 16 * j) * 68 + d4]);
            #pragma unroll
            for (int i = 0; i < 4; ++i)
                #pragma unroll
                for (int j = 0; j < 4; ++j)
                    s[i][j] += q4[i].x * k4[j].x + q4[i].y * k4[j].y +
                               q4[i].z * k4[j].z + q4[i].w * k4[j].w;
        }

        const bool diag = (kt == qt);
        #pragma unroll
        for (int i = 0; i < 4; ++i) {
            const int qi = rg + 16 * i;
            float tm = -INFINITY;
            #pragma unroll
            for (int j = 0; j < 4; ++j) {
                float sv = s[i][j] * 0.125f;
                if (diag && (cg + 16 * j) > qi) sv = -INFINITY;
                s[i][j] = sv;
                tm = fmaxf(tm, sv);
            }
            #pragma unroll
            for (int off = 1; off < 16; off <<= 1)
                tm = fmaxf(tm, __shfl_xor(tm, off, 16));

            const float mn = fmaxf(m_[i], tm);
            const float alpha = __expf(m_[i] - mn);
            float rs = 0.f;
            #pragma unroll
            for (int j = 0; j < 4; ++j) {
                float p = __expf(s[i][j] - mn);
                Ps[qi * 68 + cg + 16 * j] = p;
                rs += p;
            }
            #pragma unroll
            for (int off = 1; off < 16; off <<= 1)
                rs += __shfl_xor(rs, off, 16);

            l_[i] = l_[i] * alpha + rs;
            m_[i] = mn;
            #pragma unroll
            for (int u = 0; u < 4; ++u) O_[i][u] *= alpha;
        }

        for (int kj4 = 0; kj4 < 64; kj4 += 4) {
            float4 p4[4], v4[4];
            #pragma unroll
            for (int i = 0; i < 4; ++i)
                p4[i] = *(const float4*)(&Ps[(rg + 16 * i) * 68 + kj4]);
            #pragma unroll
            for (int u = 0; u < 4; ++u)
                v4[u] = *(const float4*)(&Vt[(cg + 16 * u) * 68 + kj4]);
            #pragma unroll
            for (int i = 0; i < 4; ++i)
                #pragma unroll
                for (int u = 0; u < 4; ++u)
                    O_[i][u] += p4[i].x * v4[u].x + p4[i].y * v4[u].y +
                                p4[i].z * v4[u].z + p4[i].w * v4[u].w;
        }
    }

    #pragma unroll
    for (int i = 0; i < 4; ++i) {
        const float inv = 1.f / l_[i];
        const long row = (long)(b * TS + qt * 64 + rg + 16 * i);
        #pragma unroll
        for (int u = 0; u < 4; ++u)
            out[row * HD + cg + 16 * u] = O_[i][u] * inv;
    }
}

// ---------------------------------------------------------------------------
extern "C" void kernel_launch(void* const* d_in, const int* in_sizes, int n_in,
                              void* d_out, int out_size, void* d_ws, size_t ws_size,
                              hipStream_t stream) {
    const float* x  = (const float*)d_in[0];
    const float* Wq = (const float*)d_in[1];
    const float* Wk = (const float*)d_in[2];
    const float* Wv = (const float*)d_in[3];
    float* out = (float*)d_out;

    const size_t nqkv = (size_t)BN * TS * HD;   // 1,048,576 elems = 4 MB each
    float* qb = (float*)d_ws;
    float* kb = qb + nqkv;
    float* vb = kb + nqkv;

    // Wt (bf16, 384 KB) lives in d_out as scratch: consumed by the GEMM,
    // then attn_kernel overwrites all of d_out with the real output.
    unsigned short* Wt = (unsigned short*)d_out;

    wt_kernel<<<48, 256, 0, stream>>>(Wq, Wk, Wv, Wt);
    qkv_mfma_kernel<<<(BN * TS) / BM, 256, 0, stream>>>(x, Wt, qb, kb, vb);
    attn_kernel<<<BN * (TS / 64), 256, 0, stream>>>(qb, kb, vb, out);
}

// Round 3
// 88.954 us; speedup vs baseline: 6.3267x; 3.1720x over previous
//
#include <hip/hip_runtime.h>
#include <math.h>

// Problem constants (match reference)
static constexpr int BN = 8;      // batch
static constexpr int TS = 2048;   // sequence length
static constexpr int CE = 1024;   // embed dim
static constexpr int HD = 64;     // head size

typedef __attribute__((ext_vector_type(8))) short bf16x8;
typedef __attribute__((ext_vector_type(4))) float f32x4;

__device__ __forceinline__ unsigned short f2bf(float f) {
    union { float f; unsigned u; } v; v.f = f;
    unsigned r = v.u + 0x7FFF + ((v.u >> 16) & 1);   // round-to-nearest-even
    return (unsigned short)(r >> 16);
}

// ---------------------------------------------------------------------------
// Kernel 0: W transpose + bf16 convert.  Wt[n][k] (n in 0..191 = q|k|v).
// ---------------------------------------------------------------------------
__global__ __launch_bounds__(256) void wt_kernel(
    const float* __restrict__ Wq, const float* __restrict__ Wk,
    const float* __restrict__ Wv, unsigned short* __restrict__ Wt)
{
    __shared__ float T[64 * 69];
    const int tid = threadIdx.x;
    const int m  = blockIdx.x >> 4;   // 0..2
    const int kt = blockIdx.x & 15;   // 0..15
    const float* W = (m == 0) ? Wq : (m == 1) ? Wk : Wv;
    const int k0 = kt * 64;

    #pragma unroll
    for (int it = 0; it < 4; ++it) {
        int idx = tid + it * 256;
        int r = idx >> 4, nq = idx & 15;
        float4 v = *(const float4*)(W + (long)(k0 + r) * HD + nq * 4);
        T[r * 69 + nq * 4 + 0] = v.x;
        T[r * 69 + nq * 4 + 1] = v.y;
        T[r * 69 + nq * 4 + 2] = v.z;
        T[r * 69 + nq * 4 + 3] = v.w;
    }
    __syncthreads();
    #pragma unroll
    for (int it = 0; it < 2; ++it) {
        int idx = tid + it * 256;
        int n = idx >> 3, kq = idx & 7;
        unsigned short h[8];
        #pragma unroll
        for (int s = 0; s < 8; ++s)
            h[s] = f2bf(T[(kq * 8 + s) * 69 + n]);
        *(uint4*)(Wt + (long)(m * 64 + n) * CE + k0 + kq * 8) = *(uint4*)h;
    }
}

// ---------------------------------------------------------------------------
// Kernel 1: QKV projection (bf16 MFMA GEMM).  Outputs now bf16:
//   qo[t][d], ko[t][d] row-major; vo TRANSPOSED per batch: vo[b][d][t].
// ---------------------------------------------------------------------------
static constexpr int BM  = 32;
static constexpr int BK  = 64;
static constexpr int LDT = BK + 8;   // 72
static constexpr int NTI = CE / BK;  // 16

__global__ __launch_bounds__(256) void qkv_mfma_kernel(
    const float* __restrict__ x, const unsigned short* __restrict__ Wt,
    unsigned short* __restrict__ qo, unsigned short* __restrict__ ko,
    unsigned short* __restrict__ vo)
{
    __shared__ __align__(16) unsigned short xL[2][BM * LDT];
    __shared__ __align__(16) unsigned short wL[2][192 * LDT];

    const int tid = threadIdx.x;
    const int l   = tid & 63, wv = tid >> 6;
    const int lr  = l & 15,  lhi = l >> 4;
    const long row0 = (long)blockIdx.x * BM;

    f32x4 acc[2][3];
    #pragma unroll
    for (int i = 0; i < 2; ++i)
        #pragma unroll
        for (int j = 0; j < 3; ++j)
            acc[i][j] = (f32x4){0.f, 0.f, 0.f, 0.f};

    float4 xr[2];
    uint4  wr[6];

    #pragma unroll
    for (int it = 0; it < 2; ++it) {
        int idx = tid + it * 256; int r = idx >> 4, kq = idx & 15;
        xr[it] = *(const float4*)(x + (row0 + r) * CE + kq * 4);
    }
    #pragma unroll
    for (int it = 0; it < 6; ++it) {
        int idx = tid + it * 256; int n = idx >> 3, kq = idx & 7;
        wr[it] = *(const uint4*)(Wt + (long)n * CE + kq * 8);
    }
    #pragma unroll
    for (int it = 0; it < 2; ++it) {
        int idx = tid + it * 256; int r = idx >> 4, kq = idx & 15;
        unsigned short h[4] = { f2bf(xr[it].x), f2bf(xr[it].y),
                                f2bf(xr[it].z), f2bf(xr[it].w) };
        *(uint2*)(&xL[0][r * LDT + kq * 4]) = *(uint2*)h;
    }
    #pragma unroll
    for (int it = 0; it < 6; ++it) {
        int idx = tid + it * 256; int n = idx >> 3, kq = idx & 7;
        *(uint4*)(&wL[0][n * LDT + kq * 8]) = wr[it];
    }
    __syncthreads();

    for (int t = 0; t < NTI; ++t) {
        const int cur = t & 1;
        const int k0n = (t + 1) * BK;
        if (t < NTI - 1) {
            #pragma unroll
            for (int it = 0; it < 2; ++it) {
                int idx = tid + it * 256; int r = idx >> 4, kq = idx & 15;
                xr[it] = *(const float4*)(x + (row0 + r) * CE + k0n + kq * 4);
            }
            #pragma unroll
            for (int it = 0; it < 6; ++it) {
                int idx = tid + it * 256; int n = idx >> 3, kq = idx & 7;
                wr[it] = *(const uint4*)(Wt + (long)n * CE + k0n + kq * 8);
            }
        }
        #pragma unroll
        for (int kk = 0; kk < 2; ++kk) {
            bf16x8 a[2], b[3];
            #pragma unroll
            for (int i = 0; i < 2; ++i)
                a[i] = *(const bf16x8*)(&xL[cur][(16 * i + lr) * LDT + kk * 32 + lhi * 8]);
            #pragma unroll
            for (int j = 0; j < 3; ++j)
                b[j] = *(const bf16x8*)(&wL[cur][(wv * 48 + 16 * j + lr) * LDT + kk * 32 + lhi * 8]);
            #pragma unroll
            for (int i = 0; i < 2; ++i)
                #pragma unroll
                for (int j = 0; j < 3; ++j)
                    acc[i][j] = __builtin_amdgcn_mfma_f32_16x16x32_bf16(
                        a[i], b[j], acc[i][j], 0, 0, 0);
        }
        if (t < NTI - 1) {
            __syncthreads();
            const int nb = cur ^ 1;
            #pragma unroll
            for (int it = 0; it < 2; ++it) {
                int idx = tid + it * 256; int r = idx >> 4, kq = idx & 15;
                unsigned short h[4] = { f2bf(xr[it].x), f2bf(xr[it].y),
                                        f2bf(xr[it].z), f2bf(xr[it].w) };
                *(uint2*)(&xL[nb][r * LDT + kq * 4]) = *(uint2*)h;
            }
            #pragma unroll
            for (int it = 0; it < 6; ++it) {
                int idx = tid + it * 256; int n = idx >> 3, kq = idx & 7;
                *(uint4*)(&wL[nb][n * LDT + kq * 8]) = wr[it];
            }
            __syncthreads();
        }
    }

    // Epilogue.  C/D: col = lane&15, row = 4*(lane>>4)+reg.
    #pragma unroll
    for (int j = 0; j < 3; ++j) {
        const int n0 = wv * 48 + 16 * j;
        if (n0 < 128) {
            unsigned short* outp = (n0 < 64) ? qo : ko;
            const int h0 = (n0 & 63) + lr;
            #pragma unroll
            for (int i = 0; i < 2; ++i)
                #pragma unroll
                for (int r = 0; r < 4; ++r) {
                    long rowg = row0 + 16 * i + lhi * 4 + r;
                    outp[rowg * HD + h0] = f2bf(acc[i][j][r]);
                }
        } else {
            const int d  = (n0 - 128) + lr;
            const int bb = (int)(row0 >> 11);
            const int t0 = (int)(row0 & 2047) + lhi * 4;
            #pragma unroll
            for (int i = 0; i < 2; ++i) {
                unsigned short h4[4];
                #pragma unroll
                for (int r = 0; r < 4; ++r) h4[r] = f2bf(acc[i][j][r]);
                *(uint2*)(vo + (((long)(bb * 64 + d)) << 11) + t0 + 16 * i) = *(uint2*)h4;
            }
        }
    }
}

// ---------------------------------------------------------------------------
// Kernel 2: causal flash attention, bf16 MFMA.
// Block = (batch, pair p): q-tiles p and 63-p (32 rows each) SEQUENTIALLY ->
// constant 33 KV-tiles of work per block; 256 blocks = 1/CU.
// Within a q-tile, the 4 waves split-K over 64-key KV tiles with private
// online-softmax state (m,l,O); merged once per q-tile via LDS.
// S^T = mfma(K, Q): q-row sits at col=lane&15 -> row reduce = 2 shfl_xor.
// P goes through a wave-private LDS buffer to become the PV A-operand.
// ---------------------------------------------------------------------------
__global__ __launch_bounds__(256) void attn_mfma_kernel(
    const unsigned short* __restrict__ qg,
    const unsigned short* __restrict__ kg,
    const unsigned short* __restrict__ vtg,
    float* __restrict__ out)
{
    __shared__ unsigned short Pl[4][32 * 72];   // per-wave P (bf16), 18.4 KB
    __shared__ float Ow[4][32 * 64];            // partial O, 32 KB
    __shared__ float Ml[4][32], Ll[4][32];

    const int tid = threadIdx.x;
    const int w  = tid >> 6;
    const int l  = tid & 63;
    const int lr = l & 15, h = l >> 4;
    const int b  = blockIdx.x >> 5;
    const int pr = blockIdx.x & 31;

    const unsigned short* qB = qg  + (long)b * TS * HD;
    const unsigned short* kB = kg  + (long)b * TS * HD;
    const unsigned short* vT = vtg + (long)b * HD * TS;
    float* outB = out + (long)b * TS * HD;

    unsigned short* Pw = &Pl[w][0];

    for (int half = 0; half < 2; ++half) {
        const int qt = half ? (63 - pr) : pr;
        const int q0 = qt * 32;
        const int NT = (qt + 2) >> 1;   // KV tiles of 64 keys

        // Q B-frags [qf][ks]: Q[q0+16qf+lr][32ks+8h + j]
        bf16x8 Qf[2][2];
        #pragma unroll
        for (int qf = 0; qf < 2; ++qf)
            #pragma unroll
            for (int ks = 0; ks < 2; ++ks)
                Qf[qf][ks] = *(const bf16x8*)(qB + (q0 + 16 * qf + lr) * HD + 32 * ks + 8 * h);

        f32x4 O[2][4];
        #pragma unroll
        for (int rf = 0; rf < 2; ++rf)
            #pragma unroll
            for (int cf = 0; cf < 4; ++cf)
                O[rf][cf] = (f32x4){0.f, 0.f, 0.f, 0.f};
        float mrow[2] = {-1e30f, -1e30f};
        float lrow[2] = {0.f, 0.f};

        for (int kt = w; kt < NT; kt += 4) {
            const int key0 = kt * 64;
            // K A-frags [kf][ks], V^T B-frags [cf][ks] — direct global (L2)
            bf16x8 Kf[4][2], Vf[4][2];
            #pragma unroll
            for (int kf = 0; kf < 4; ++kf)
                #pragma unroll
                for (int ks = 0; ks < 2; ++ks)
                    Kf[kf][ks] = *(const bf16x8*)(kB + (key0 + 16 * kf + lr) * HD + 32 * ks + 8 * h);
            #pragma unroll
            for (int cf = 0; cf < 4; ++cf)
                #pragma unroll
                for (int ks = 0; ks < 2; ++ks)
                    Vf[cf][ks] = *(const bf16x8*)(vT + (16 * cf + lr) * TS + key0 + 32 * ks + 8 * h);

            // S^T[key][q]: rows=keys (4 frags), cols=q (2 frags)
            f32x4 st[4][2];
            #pragma unroll
            for (int kf = 0; kf < 4; ++kf)
                #pragma unroll
                for (int qf = 0; qf < 2; ++qf)
                    st[kf][qf] = (f32x4){0.f, 0.f, 0.f, 0.f};
            #pragma unroll
            for (int ks = 0; ks < 2; ++ks)
                #pragma unroll
                for (int kf = 0; kf < 4; ++kf)
                    #pragma unroll
                    for (int qf = 0; qf < 2; ++qf)
                        st[kf][qf] = __builtin_amdgcn_mfma_f32_16x16x32_bf16(
                            Kf[kf][ks], Qf[qf][ks], st[kf][qf], 0, 0, 0);

            const bool lastt = (kt == NT - 1);
            float alpha[2];
            #pragma unroll
            for (int qf = 0; qf < 2; ++qf) {
                const int qrow = q0 + 16 * qf + lr;
                float tm = -1e30f;
                #pragma unroll
                for (int kf = 0; kf < 4; ++kf)
                    #pragma unroll
                    for (int r = 0; r < 4; ++r) {
                        float sv = st[kf][qf][r] * 0.125f;
                        if (lastt && (key0 + 16 * kf + 4 * h + r) > qrow) sv = -1e30f;
                        st[kf][qf][r] = sv;
                        tm = fmaxf(tm, sv);
                    }
                tm = fmaxf(tm, __shfl_xor(tm, 16));
                tm = fmaxf(tm, __shfl_xor(tm, 32));
                const float mn = fmaxf(mrow[qf], tm);
                alpha[qf] = __expf(mrow[qf] - mn);
                mrow[qf] = mn;
                float rs = 0.f;
                #pragma unroll
                for (int kf = 0; kf < 4; ++kf)
                    #pragma unroll
                    for (int r = 0; r < 4; ++r) {
                        float p = __expf(st[kf][qf][r] - mn);
                        st[kf][qf][r] = p;
                        rs += p;
                    }
                rs += __shfl_xor(rs, 16);
                rs += __shfl_xor(rs, 32);
                lrow[qf] = lrow[qf] * alpha[qf] + rs;
                // pack P row (bf16 pairs) -> wave-private LDS
                #pragma unroll
                for (int kf = 0; kf < 4; ++kf) {
                    unsigned a01 = (unsigned)f2bf(st[kf][qf][0]) |
                                   ((unsigned)f2bf(st[kf][qf][1]) << 16);
                    unsigned a23 = (unsigned)f2bf(st[kf][qf][2]) |
                                   ((unsigned)f2bf(st[kf][qf][3]) << 16);
                    unsigned short* pp = Pw + (16 * qf + lr) * 72 + 16 * kf + 4 * h;
                    *(unsigned*)(pp)     = a01;
                    *(unsigned*)(pp + 2) = a23;
                }
            }

            // O *= alpha (alpha for O-row q=16rf+4h+r lives in lane 4h+r)
            #pragma unroll
            for (int rf = 0; rf < 2; ++rf)
                #pragma unroll
                for (int r = 0; r < 4; ++r) {
                    float aO = __shfl(alpha[rf], 4 * h + r);
                    #pragma unroll
                    for (int cf = 0; cf < 4; ++cf)
                        O[rf][cf][r] *= aO;
                }

            // P A-frags from LDS, then PV accumulate
            bf16x8 pa[2][2];
            #pragma unroll
            for (int rf = 0; rf < 2; ++rf)
                #pragma unroll
                for (int ks = 0; ks < 2; ++ks)
                    pa[rf][ks] = *(const bf16x8*)(Pw + (16 * rf + lr) * 72 + 32 * ks + 8 * h);
            #pragma unroll
            for (int ks = 0; ks < 2; ++ks)
                #pragma unroll
                for (int rf = 0; rf < 2; ++rf)
                    #pragma unroll
                    for (int cf = 0; cf < 4; ++cf)
                        O[rf][cf] = __builtin_amdgcn_mfma_f32_16x16x32_bf16(
                            pa[rf][ks], Vf[cf][ks], O[rf][cf], 0, 0, 0);
        }

        // write this wave's partials
        #pragma unroll
        for (int rf = 0; rf < 2; ++rf)
            #pragma unroll
            for (int cf = 0; cf < 4; ++cf)
                #pragma unroll
                for (int r = 0; r < 4; ++r)
                    Ow[w][(16 * rf + 4 * h + r) * 64 + 16 * cf + lr] = O[rf][cf][r];
        if (h == 0) {
            #pragma unroll
            for (int qf = 0; qf < 2; ++qf) {
                Ml[w][16 * qf + lr] = mrow[qf];
                Ll[w][16 * qf + lr] = lrow[qf];
            }
        }
        __syncthreads();

        // merge 4 partials: thread -> (q = tid>>3, d0 = (tid&7)*8)
        {
            const int q  = tid >> 3;
            const int d0 = (tid & 7) * 8;
            float mM = -1e30f;
            #pragma unroll
            for (int w2 = 0; w2 < 4; ++w2) mM = fmaxf(mM, Ml[w2][q]);
            float lS = 0.f;
            float a8[8] = {0.f,0.f,0.f,0.f,0.f,0.f,0.f,0.f};
            #pragma unroll
            for (int w2 = 0; w2 < 4; ++w2) {
                float sc = __expf(Ml[w2][q] - mM);
                lS += Ll[w2][q] * sc;
                #pragma unroll
                for (int e = 0; e < 8; ++e)
                    a8[e] += sc * Ow[w2][q * 64 + d0 + e];
            }
            const float inv = 1.f / lS;
            float4 o1 = {a8[0]*inv, a8[1]*inv, a8[2]*inv, a8[3]*inv};
            float4 o2 = {a8[4]*inv, a8[5]*inv, a8[6]*inv, a8[7]*inv};
            *(float4*)(outB + (long)(q0 + q) * HD + d0)     = o1;
            *(float4*)(outB + (long)(q0 + q) * HD + d0 + 4) = o2;
        }
        __syncthreads();
    }
}

// ---------------------------------------------------------------------------
extern "C" void kernel_launch(void* const* d_in, const int* in_sizes, int n_in,
                              void* d_out, int out_size, void* d_ws, size_t ws_size,
                              hipStream_t stream) {
    const float* x  = (const float*)d_in[0];
    const float* Wq = (const float*)d_in[1];
    const float* Wk = (const float*)d_in[2];
    const float* Wv = (const float*)d_in[3];
    float* out = (float*)d_out;

    const size_t nqkv = (size_t)BN * TS * HD;   // 1,048,576 elems
    unsigned short* qb = (unsigned short*)d_ws;          // 2 MB bf16 [b*t][d]
    unsigned short* kb = qb + nqkv;                      // 2 MB bf16 [b*t][d]
    unsigned short* vt = kb + nqkv;                      // 2 MB bf16 [b][d][t]

    // Wt (bf16, 384 KB) in d_out scratch; consumed before attn overwrites.
    unsigned short* Wt = (unsigned short*)d_out;

    wt_kernel<<<48, 256, 0, stream>>>(Wq, Wk, Wv, Wt);
    qkv_mfma_kernel<<<(BN * TS) / BM, 256, 0, stream>>>(x, Wt, qb, kb, vt);
    attn_mfma_kernel<<<BN * 32, 256, 0, stream>>>(qb, kb, vt, out);
}

// Round 4
// 60.016 us; speedup vs baseline: 9.3772x; 1.4822x over previous
//
#include <hip/hip_runtime.h>
#include <math.h>

// Problem constants (match reference)
static constexpr int BN = 8;      // batch
static constexpr int TS = 2048;   // sequence length
static constexpr int CE = 1024;   // embed dim
static constexpr int HD = 64;     // head size

typedef __attribute__((ext_vector_type(8))) short bf16x8;
typedef __attribute__((ext_vector_type(4))) float f32x4;

__device__ __forceinline__ unsigned short f2bf(float f) {
    union { float f; unsigned u; } v; v.f = f;
    unsigned r = v.u + 0x7FFF + ((v.u >> 16) & 1);   // round-to-nearest-even
    return (unsigned short)(r >> 16);
}

// Raw barrier: lgkmcnt(0) drains our ds_writes for cross-wave visibility,
// "memory" clobber stops LDS-op reordering across it.  Crucially it does NOT
// drain vmcnt -> global prefetch loads stay in flight across K-steps (T4).
#define BARRIER() do { asm volatile("s_waitcnt lgkmcnt(0)" ::: "memory"); \
                       __builtin_amdgcn_s_barrier();                      \
                       asm volatile("" ::: "memory"); } while (0)

// ---------------------------------------------------------------------------
// Kernel 0: W transpose + bf16 convert.  Wt[n][k] (n in 0..191 = q|k|v).
// ---------------------------------------------------------------------------
__global__ __launch_bounds__(256) void wt_kernel(
    const float* __restrict__ Wq, const float* __restrict__ Wk,
    const float* __restrict__ Wv, unsigned short* __restrict__ Wt)
{
    __shared__ float T[64 * 69];
    const int tid = threadIdx.x;
    const int m  = blockIdx.x >> 4;   // 0..2
    const int kt = blockIdx.x & 15;   // 0..15
    const float* W = (m == 0) ? Wq : (m == 1) ? Wk : Wv;
    const int k0 = kt * 64;

    #pragma unroll
    for (int it = 0; it < 4; ++it) {
        int idx = tid + it * 256;
        int r = idx >> 4, nq = idx & 15;
        float4 v = *(const float4*)(W + (long)(k0 + r) * HD + nq * 4);
        T[r * 69 + nq * 4 + 0] = v.x;
        T[r * 69 + nq * 4 + 1] = v.y;
        T[r * 69 + nq * 4 + 2] = v.z;
        T[r * 69 + nq * 4 + 3] = v.w;
    }
    __syncthreads();
    #pragma unroll
    for (int it = 0; it < 2; ++it) {
        int idx = tid + it * 256;
        int n = idx >> 3, kq = idx & 7;
        unsigned short h[8];
        #pragma unroll
        for (int s = 0; s < 8; ++s)
            h[s] = f2bf(T[(kq * 8 + s) * 69 + n]);
        *(uint4*)(Wt + (long)(m * 64 + n) * CE + k0 + kq * 8) = *(uint4*)h;
    }
}

// ---------------------------------------------------------------------------
// Kernel 1: QKV projection (bf16 MFMA GEMM), HBM-streaming structure.
//   - 512 blocks x 256 threads (BM=32), 2 blocks/CU.
//   - W fragments loaded DIRECTLY from global (L2-resident), 1 step ahead.
//   - x staged to LDS as bf16 (XOR-swizzled 16B granules), double-buffered,
//     with a 2-K-step-deep register prefetch; one raw barrier per K-step,
//     vmcnt never drained in the loop.
// Outputs bf16: qo[t][d], ko[t][d] row-major; vo transposed: vo[b][d][t].
// ---------------------------------------------------------------------------
static constexpr int NTI = CE / 64;  // 16 K-steps of 64

__global__ __launch_bounds__(256) void qkv_mfma_kernel(
    const float* __restrict__ x, const unsigned short* __restrict__ Wt,
    unsigned short* __restrict__ qo, unsigned short* __restrict__ ko,
    unsigned short* __restrict__ vo)
{
    __shared__ __align__(16) unsigned short xL0[32 * 64];
    __shared__ __align__(16) unsigned short xL1[32 * 64];

    const int tid = threadIdx.x;
    const int l  = tid & 63, w = tid >> 6;
    const int lr = l & 15,  h = l >> 4;
    const long row0 = (long)blockIdx.x * 32;

    // staging role: thread -> (row sr, 16B-granule sq), swizzled slot
    const int sr = tid >> 3;            // 0..31
    const int sq = tid & 7;             // 0..7
    const int slot = sq ^ (sr & 7);
    const float* xgr = x + (row0 + sr) * CE + sq * 8;
    unsigned short* xw0 = &xL0[sr * 64 + slot * 8];
    unsigned short* xw1 = &xL1[sr * 64 + slot * 8];

    // this wave's W fragment bases (cols 48w .. 48w+47)
    const unsigned short* wb0 = Wt + (long)(w * 48 + 0  + lr) * CE + 8 * h;
    const unsigned short* wb1 = Wt + (long)(w * 48 + 16 + lr) * CE + 8 * h;
    const unsigned short* wb2 = Wt + (long)(w * 48 + 32 + lr) * CE + 8 * h;

    // A-frag swizzled LDS offsets (shorts) for kk=0/1
    const int sw0 = ((0 + h) ^ (lr & 7)) * 8;
    const int sw1 = ((4 + h) ^ (lr & 7)) * 8;

    f32x4 acc[2][3];
    #pragma unroll
    for (int i = 0; i < 2; ++i)
        #pragma unroll
        for (int j = 0; j < 3; ++j)
            acc[i][j] = (f32x4){0.f, 0.f, 0.f, 0.f};

    bf16x8 bA[6], bB[6];     // W frags [j*2+kk], current / next K-step
    float4 Ro0, Ro1, Re0, Re1;  // x prefetch: odd steps (d1,d3,..), even (d2,d4,..)

    // ---- prologue: d0 staged immediately; d1,d2 into regs; W(0) into bA
    {
        float4 t0 = *(const float4*)(xgr);
        float4 t1 = *(const float4*)(xgr + 4);
        Ro0 = *(const float4*)(xgr + 64);
        Ro1 = *(const float4*)(xgr + 68);
        Re0 = *(const float4*)(xgr + 128);
        Re1 = *(const float4*)(xgr + 132);
        #pragma unroll
        for (int j = 0; j < 3; ++j) {
            const unsigned short* wbj = (j == 0) ? wb0 : (j == 1) ? wb1 : wb2;
            bA[j * 2 + 0] = *(const bf16x8*)(wbj);
            bA[j * 2 + 1] = *(const bf16x8*)(wbj + 32);
        }
        unsigned short hh[8] = { f2bf(t0.x), f2bf(t0.y), f2bf(t0.z), f2bf(t0.w),
                                 f2bf(t1.x), f2bf(t1.y), f2bf(t1.z), f2bf(t1.w) };
        *(uint4*)xw0 = *(uint4*)hh;
    }
    BARRIER();

    #define STAGE(dst, r0, r1) do {                                          \
        unsigned short hh[8] = { f2bf((r0).x), f2bf((r0).y), f2bf((r0).z),   \
                                 f2bf((r0).w), f2bf((r1).x), f2bf((r1).y),   \
                                 f2bf((r1).z), f2bf((r1).w) };               \
        *(uint4*)(dst) = *(uint4*)hh; } while (0)

    #define LOADW(arr, t) do {                                               \
        (arr)[0] = *(const bf16x8*)(wb0 + (t) * 64);                         \
        (arr)[1] = *(const bf16x8*)(wb0 + (t) * 64 + 32);                    \
        (arr)[2] = *(const bf16x8*)(wb1 + (t) * 64);                         \
        (arr)[3] = *(const bf16x8*)(wb1 + (t) * 64 + 32);                    \
        (arr)[4] = *(const bf16x8*)(wb2 + (t) * 64);                         \
        (arr)[5] = *(const bf16x8*)(wb2 + (t) * 64 + 32);  } while (0)

    #define COMPUTE(buf, b) do {                                             \
        _Pragma("unroll")                                                    \
        for (int kk = 0; kk < 2; ++kk) {                                     \
            const int ss = kk ? sw1 : sw0;                                   \
            bf16x8 a0 = *(const bf16x8*)(&(buf)[lr * 64 + ss]);              \
            bf16x8 a1 = *(const bf16x8*)(&(buf)[(16 + lr) * 64 + ss]);       \
            _Pragma("unroll")                                                \
            for (int j = 0; j < 3; ++j) {                                    \
                acc[0][j] = __builtin_amdgcn_mfma_f32_16x16x32_bf16(         \
                    a0, (b)[j * 2 + kk], acc[0][j], 0, 0, 0);                \
                acc[1][j] = __builtin_amdgcn_mfma_f32_16x16x32_bf16(         \
                    a1, (b)[j * 2 + kk], acc[1][j], 0, 0, 0);                \
            }                                                                \
        } } while (0)

    for (int t = 0; t < NTI; t += 2) {
        // ---- even step t: compute buf0 with bA
        STAGE(xw1, Ro0, Ro1);                       // stage d(t+1) -> buf1
        if (t + 3 < NTI) {                          // issue d(t+3) (2 deep)
            Ro0 = *(const float4*)(xgr + (t + 3) * 64);
            Ro1 = *(const float4*)(xgr + (t + 3) * 64 + 4);
        }
        LOADW(bB, t + 1);                           // W for step t+1 (L2)
        COMPUTE(xL0, bA);
        BARRIER();

        // ---- odd step t+1: compute buf1 with bB
        if (t + 2 < NTI) {
            STAGE(xw0, Re0, Re1);                   // stage d(t+2) -> buf0
            if (t + 4 < NTI) {
                Re0 = *(const float4*)(xgr + (t + 4) * 64);
                Re1 = *(const float4*)(xgr + (t + 4) * 64 + 4);
            }
            LOADW(bA, t + 2);                       // W for step t+2
        }
        COMPUTE(xL1, bB);
        if (t + 2 < NTI) BARRIER();
    }

    // ---- epilogue.  C/D: col = lane&15, row = 4*(lane>>4)+reg.
    #pragma unroll
    for (int j = 0; j < 3; ++j) {
        const int n0 = w * 48 + 16 * j;
        if (n0 < 128) {
            unsigned short* outp = (n0 < 64) ? qo : ko;
            const int h0 = (n0 & 63) + lr;
            #pragma unroll
            for (int i = 0; i < 2; ++i)
                #pragma unroll
                for (int r = 0; r < 4; ++r) {
                    long rowg = row0 + 16 * i + h * 4 + r;
                    outp[rowg * HD + h0] = f2bf(acc[i][j][r]);
                }
        } else {
            const int d  = (n0 - 128) + lr;
            const int bb = (int)(row0 >> 11);
            const int t0 = (int)(row0 & 2047) + h * 4;
            #pragma unroll
            for (int i = 0; i < 2; ++i) {
                unsigned short h4[4];
                #pragma unroll
                for (int r = 0; r < 4; ++r) h4[r] = f2bf(acc[i][j][r]);
                *(uint2*)(vo + (((long)(bb * 64 + d)) << 11) + t0 + 16 * i) = *(uint2*)h4;
            }
        }
    }
    #undef STAGE
    #undef LOADW
    #undef COMPUTE
}

// ---------------------------------------------------------------------------
// Kernel 2: causal flash attention, bf16 MFMA (unchanged from R3).
// ---------------------------------------------------------------------------
__global__ __launch_bounds__(256) void attn_mfma_kernel(
    const unsigned short* __restrict__ qg,
    const unsigned short* __restrict__ kg,
    const unsigned short* __restrict__ vtg,
    float* __restrict__ out)
{
    __shared__ unsigned short Pl[4][32 * 72];   // per-wave P (bf16)
    __shared__ float Ow[4][32 * 64];            // partial O
    __shared__ float Ml[4][32], Ll[4][32];

    const int tid = threadIdx.x;
    const int w  = tid >> 6;
    const int l  = tid & 63;
    const int lr = l & 15, h = l >> 4;
    const int b  = blockIdx.x >> 5;
    const int pr = blockIdx.x & 31;

    const unsigned short* qB = qg  + (long)b * TS * HD;
    const unsigned short* kB = kg  + (long)b * TS * HD;
    const unsigned short* vT = vtg + (long)b * HD * TS;
    float* outB = out + (long)b * TS * HD;

    unsigned short* Pw = &Pl[w][0];

    for (int half = 0; half < 2; ++half) {
        const int qt = half ? (63 - pr) : pr;
        const int q0 = qt * 32;
        const int NT = (qt + 2) >> 1;   // KV tiles of 64 keys

        bf16x8 Qf[2][2];
        #pragma unroll
        for (int qf = 0; qf < 2; ++qf)
            #pragma unroll
            for (int ks = 0; ks < 2; ++ks)
                Qf[qf][ks] = *(const bf16x8*)(qB + (q0 + 16 * qf + lr) * HD + 32 * ks + 8 * h);

        f32x4 O[2][4];
        #pragma unroll
        for (int rf = 0; rf < 2; ++rf)
            #pragma unroll
            for (int cf = 0; cf < 4; ++cf)
                O[rf][cf] = (f32x4){0.f, 0.f, 0.f, 0.f};
        float mrow[2] = {-1e30f, -1e30f};
        float lrow[2] = {0.f, 0.f};

        for (int kt = w; kt < NT; kt += 4) {
            const int key0 = kt * 64;
            bf16x8 Kf[4][2], Vf[4][2];
            #pragma unroll
            for (int kf = 0; kf < 4; ++kf)
                #pragma unroll
                for (int ks = 0; ks < 2; ++ks)
                    Kf[kf][ks] = *(const bf16x8*)(kB + (key0 + 16 * kf + lr) * HD + 32 * ks + 8 * h);
            #pragma unroll
            for (int cf = 0; cf < 4; ++cf)
                #pragma unroll
                for (int ks = 0; ks < 2; ++ks)
                    Vf[cf][ks] = *(const bf16x8*)(vT + (16 * cf + lr) * TS + key0 + 32 * ks + 8 * h);

            f32x4 st[4][2];
            #pragma unroll
            for (int kf = 0; kf < 4; ++kf)
                #pragma unroll
                for (int qf = 0; qf < 2; ++qf)
                    st[kf][qf] = (f32x4){0.f, 0.f, 0.f, 0.f};
            #pragma unroll
            for (int ks = 0; ks < 2; ++ks)
                #pragma unroll
                for (int kf = 0; kf < 4; ++kf)
                    #pragma unroll
                    for (int qf = 0; qf < 2; ++qf)
                        st[kf][qf] = __builtin_amdgcn_mfma_f32_16x16x32_bf16(
                            Kf[kf][ks], Qf[qf][ks], st[kf][qf], 0, 0, 0);

            const bool lastt = (kt == NT - 1);
            float alpha[2];
            #pragma unroll
            for (int qf = 0; qf < 2; ++qf) {
                const int qrow = q0 + 16 * qf + lr;
                float tm = -1e30f;
                #pragma unroll
                for (int kf = 0; kf < 4; ++kf)
                    #pragma unroll
                    for (int r = 0; r < 4; ++r) {
                        float sv = st[kf][qf][r] * 0.125f;
                        if (lastt && (key0 + 16 * kf + 4 * h + r) > qrow) sv = -1e30f;
                        st[kf][qf][r] = sv;
                        tm = fmaxf(tm, sv);
                    }
                tm = fmaxf(tm, __shfl_xor(tm, 16));
                tm = fmaxf(tm, __shfl_xor(tm, 32));
                const float mn = fmaxf(mrow[qf], tm);
                alpha[qf] = __expf(mrow[qf] - mn);
                mrow[qf] = mn;
                float rs = 0.f;
                #pragma unroll
                for (int kf = 0; kf < 4; ++kf)
                    #pragma unroll
                    for (int r = 0; r < 4; ++r) {
                        float p = __expf(st[kf][qf][r] - mn);
                        st[kf][qf][r] = p;
                        rs += p;
                    }
                rs += __shfl_xor(rs, 16);
                rs += __shfl_xor(rs, 32);
                lrow[qf] = lrow[qf] * alpha[qf] + rs;
                #pragma unroll
                for (int kf = 0; kf < 4; ++kf) {
                    unsigned a01 = (unsigned)f2bf(st[kf][qf][0]) |
                                   ((unsigned)f2bf(st[kf][qf][1]) << 16);
                    unsigned a23 = (unsigned)f2bf(st[kf][qf][2]) |
                                   ((unsigned)f2bf(st[kf][qf][3]) << 16);
                    unsigned short* pp = Pw + (16 * qf + lr) * 72 + 16 * kf + 4 * h;
                    *(unsigned*)(pp)     = a01;
                    *(unsigned*)(pp + 2) = a23;
                }
            }

            #pragma unroll
            for (int rf = 0; rf < 2; ++rf)
                #pragma unroll
                for (int r = 0; r < 4; ++r) {
                    float aO = __shfl(alpha[rf], 4 * h + r);
                    #pragma unroll
                    for (int cf = 0; cf < 4; ++cf)
                        O[rf][cf][r] *= aO;
                }

            bf16x8 pa[2][2];
            #pragma unroll
            for (int rf = 0; rf < 2; ++rf)
                #pragma unroll
                for (int ks = 0; ks < 2; ++ks)
                    pa[rf][ks] = *(const bf16x8*)(Pw + (16 * rf + lr) * 72 + 32 * ks + 8 * h);
            #pragma unroll
            for (int ks = 0; ks < 2; ++ks)
                #pragma unroll
                for (int rf = 0; rf < 2; ++rf)
                    #pragma unroll
                    for (int cf = 0; cf < 4; ++cf)
                        O[rf][cf] = __builtin_amdgcn_mfma_f32_16x16x32_bf16(
                            pa[rf][ks], Vf[cf][ks], O[rf][cf], 0, 0, 0);
        }

        #pragma unroll
        for (int rf = 0; rf < 2; ++rf)
            #pragma unroll
            for (int cf = 0; cf < 4; ++cf)
                #pragma unroll
                for (int r = 0; r < 4; ++r)
                    Ow[w][(16 * rf + 4 * h + r) * 64 + 16 * cf + lr] = O[rf][cf][r];
        if (h == 0) {
            #pragma unroll
            for (int qf = 0; qf < 2; ++qf) {
                Ml[w][16 * qf + lr] = mrow[qf];
                Ll[w][16 * qf + lr] = lrow[qf];
            }
        }
        __syncthreads();

        {
            const int q  = tid >> 3;
            const int d0 = (tid & 7) * 8;
            float mM = -1e30f;
            #pragma unroll
            for (int w2 = 0; w2 < 4; ++w2) mM = fmaxf(mM, Ml[w2][q]);
            float lS = 0.f;
            float a8[8] = {0.f,0.f,0.f,0.f,0.f,0.f,0.f,0.f};
            #pragma unroll
            for (int w2 = 0; w2 < 4; ++w2) {
                float sc = __expf(Ml[w2][q] - mM);
                lS += Ll[w2][q] * sc;
                #pragma unroll
                for (int e = 0; e < 8; ++e)
                    a8[e] += sc * Ow[w2][q * 64 + d0 + e];
            }
            const float inv = 1.f / lS;
            float4 o1 = {a8[0]*inv, a8[1]*inv, a8[2]*inv, a8[3]*inv};
            float4 o2 = {a8[4]*inv, a8[5]*inv, a8[6]*inv, a8[7]*inv};
            *(float4*)(outB + (long)(q0 + q) * HD + d0)     = o1;
            *(float4*)(outB + (long)(q0 + q) * HD + d0 + 4) = o2;
        }
        __syncthreads();
    }
}

// ---------------------------------------------------------------------------
extern "C" void kernel_launch(void* const* d_in, const int* in_sizes, int n_in,
                              void* d_out, int out_size, void* d_ws, size_t ws_size,
                              hipStream_t stream) {
    const float* x  = (const float*)d_in[0];
    const float* Wq = (const float*)d_in[1];
    const float* Wk = (const float*)d_in[2];
    const float* Wv = (const float*)d_in[3];
    float* out = (float*)d_out;

    const size_t nqkv = (size_t)BN * TS * HD;   // 1,048,576 elems
    unsigned short* qb = (unsigned short*)d_ws;          // 2 MB bf16 [b*t][d]
    unsigned short* kb = qb + nqkv;                      // 2 MB bf16 [b*t][d]
    unsigned short* vt = kb + nqkv;                      // 2 MB bf16 [b][d][t]

    // Wt (bf16, 384 KB) in d_out scratch; consumed before attn overwrites.
    unsigned short* Wt = (unsigned short*)d_out;

    wt_kernel<<<48, 256, 0, stream>>>(Wq, Wk, Wv, Wt);
    qkv_mfma_kernel<<<(BN * TS) / 32, 256, 0, stream>>>(x, Wt, qb, kb, vt);
    attn_mfma_kernel<<<BN * 32, 256, 0, stream>>>(qb, kb, vt, out);
}